// Round 4
// baseline (1264.288 us; speedup 1.0000x reference)
//
#include <hip/hip_runtime.h>

// 2-layer GCN, N=100000, E=3200000, feats 512 -> 16 -> 40.
//
// out[d] = dinv[d]*(sum_{s->d} h[s]*dinv[s] + h[d]*dinv[d]) + b,  dinv = rsqrt(deg+1)
//
// Round-4 structure (replaces CSR build whose k_fill scatter was 280us / 195MB writes):
//  * Edges partitioned into 256-node dst-buckets as packed u32 (dense writes, no
//    random 4B scatter).  Bucket sizes derived from deg (no extra edge pass).
//  * Aggregation: one block per bucket, LDS accumulator [256][17-stride] with
//    ds_add_f32 atomics; gathers h[src] rows (L2-resident) coalesced per lane.
//  * W2 postponed past aggregation; layer-2 agg fuses W2 + b2 + log_softmax.

#define NFEAT_IN 512
#define NF1 16
#define NF2 40
#define BK_LG 8          // 256 nodes per bucket
#define ASTR 17          // LDS accumulator row stride (bank-conflict-free atomics)
#define P1B 256          // partition blocks
#define TILE 4096        // edges per partition tile

// ---------------- degree + dinv ----------------
__global__ void k_count(const int* __restrict__ dst, int* __restrict__ deg, int E) {
  int e = blockIdx.x * 256 + threadIdx.x;
  if (e < E) atomicAdd(&deg[dst[e]], 1);
}

__global__ void k_dinv(const int* __restrict__ deg, float* __restrict__ dinv, int n) {
  int v = blockIdx.x * 256 + threadIdx.x;
  if (v < n) dinv[v] = rsqrtf((float)(deg[v] + 1));  // +1 self-loop
}

// ---------------- bucket sizes from deg (block reduce over 256 nodes) ----------------
__global__ void k_bsz(const int* __restrict__ deg, int* __restrict__ bsz, int n) {
  __shared__ int s[256];
  int v = (blockIdx.x << BK_LG) + threadIdx.x;
  s[threadIdx.x] = (v < n) ? deg[v] : 0;
  __syncthreads();
#pragma unroll
  for (int o = 128; o > 0; o >>= 1) {
    if (threadIdx.x < o) s[threadIdx.x] += s[threadIdx.x + o];
    __syncthreads();
  }
  if (threadIdx.x == 0) bsz[blockIdx.x] = s[0];
}

// ---------------- scan of bucket sizes (nbk <= 512), one block ----------------
__global__ void k_scanb(const int* __restrict__ bsz, int* __restrict__ boff,
                        int* __restrict__ gcur, int nbk, int E) {
  __shared__ int s[512];
  int t = threadIdx.x;
  s[t] = (t < nbk) ? bsz[t] : 0;
  __syncthreads();
#pragma unroll
  for (int o = 1; o < 512; o <<= 1) {
    int v = (t >= o) ? s[t - o] : 0;
    __syncthreads();
    s[t] += v;
    __syncthreads();
  }
  if (t < nbk) {
    int ex = s[t] - bsz[t];  // exclusive
    boff[t] = ex;
    gcur[t] = ex;
  }
  if (t == 0) boff[nbk] = E;
}

// ---------------- bucket partition: ebuf[] = (dst&255)<<17 | src, grouped by bucket ----------------
__global__ void k_part(const int* __restrict__ src, const int* __restrict__ dst,
                       int* __restrict__ gcur, unsigned int* __restrict__ ebuf,
                       int E, int nbk) {
  __shared__ int hist[512];
  __shared__ int hbase[512];
  int chunk = (E + P1B - 1) / P1B;
  int beg = blockIdx.x * chunk;
  int end = min(E, beg + chunk);
  for (int t0 = beg; t0 < end; t0 += TILE) {
    int t1 = min(end, t0 + TILE);
    for (int i = threadIdx.x; i < nbk; i += 256) hist[i] = 0;
    __syncthreads();
    for (int i = t0 + threadIdx.x; i < t1; i += 256)
      atomicAdd(&hist[dst[i] >> BK_LG], 1);
    __syncthreads();
    for (int i = threadIdx.x; i < nbk; i += 256) {
      int c = hist[i];
      hbase[i] = (c > 0) ? atomicAdd(&gcur[i], c) : 0;
      hist[i] = 0;  // becomes rank counter
    }
    __syncthreads();
    for (int i = t0 + threadIdx.x; i < t1; i += 256) {
      int d = dst[i], s = src[i];
      int b = d >> BK_LG;
      int r = atomicAdd(&hist[b], 1);
      ebuf[hbase[b] + r] = ((unsigned)(d & ((1 << BK_LG) - 1)) << 17) | (unsigned)s;
    }
    __syncthreads();
  }
}

// ---------------- layer-1 gemm: h1s[v][f] = dinv[v]*sum_k x[v][k]*W1[k][f] ----------------
__global__ void k_gemm1(const float* __restrict__ x, const float* __restrict__ W1,
                        const float* __restrict__ dinv, float* __restrict__ h1s, int n) {
  __shared__ float Wt[NF1][NFEAT_IN + 4];
  for (int i = threadIdx.x; i < NFEAT_IN * NF1; i += 256) {
    int k = i >> 4, f = i & 15;
    Wt[f][k] = W1[i];
  }
  __syncthreads();
  int tid = blockIdx.x * 256 + threadIdx.x;
  int v = tid >> 4, f = tid & 15;
  if (v >= n) return;
  const float4* xr = (const float4*)(x + (size_t)v * NFEAT_IN);
  const float4* wr = (const float4*)(&Wt[f][0]);
  float acc = 0.f;
#pragma unroll 8
  for (int k4 = 0; k4 < NFEAT_IN / 4; ++k4) {
    float4 a = xr[k4], w = wr[k4];
    acc = fmaf(a.x, w.x, acc);
    acc = fmaf(a.y, w.y, acc);
    acc = fmaf(a.z, w.z, acc);
    acc = fmaf(a.w, w.w, acc);
  }
  h1s[tid] = acc * dinv[v];
}

// ---------------- layer-1 aggregation: as2 = relu(dinv*(agg+self)+b1)*dinv ----------------
__global__ __launch_bounds__(512) void k_aggL1(
    const unsigned int* __restrict__ ebuf, const int* __restrict__ boff,
    const float* __restrict__ h1s, const float* __restrict__ dinv,
    const float* __restrict__ b1, float* __restrict__ as2, int n) {
  __shared__ float acc[256 * ASTR];  // 17.4 KB
  __shared__ float b1s[NF1];
  if (threadIdx.x < NF1) b1s[threadIdx.x] = b1[threadIdx.x];
  for (int i = threadIdx.x; i < 256 * ASTR; i += 512) acc[i] = 0.f;
  __syncthreads();
  int b = blockIdx.x;
  int e1 = boff[b + 1];
  for (int e = boff[b] + threadIdx.x; e < e1; e += 512) {
    unsigned p = ebuf[e];
    int s = p & 0x1FFFF;
    int dl = p >> 17;
    const float4* hr = (const float4*)(h1s + (size_t)s * NF1);
    float4 a0 = hr[0], a1 = hr[1], a2 = hr[2], a3 = hr[3];
    float* ar = &acc[dl * ASTR];
    atomicAdd(&ar[0], a0.x);  atomicAdd(&ar[1], a0.y);
    atomicAdd(&ar[2], a0.z);  atomicAdd(&ar[3], a0.w);
    atomicAdd(&ar[4], a1.x);  atomicAdd(&ar[5], a1.y);
    atomicAdd(&ar[6], a1.z);  atomicAdd(&ar[7], a1.w);
    atomicAdd(&ar[8], a2.x);  atomicAdd(&ar[9], a2.y);
    atomicAdd(&ar[10], a2.z); atomicAdd(&ar[11], a2.w);
    atomicAdd(&ar[12], a3.x); atomicAdd(&ar[13], a3.y);
    atomicAdd(&ar[14], a3.z); atomicAdd(&ar[15], a3.w);
  }
  __syncthreads();
  int v0 = b << BK_LG;
  int nn = min(256, n - v0);
  for (int v = threadIdx.x; v < nn; v += 512) {
    float dv = dinv[v0 + v];
    const float4* hr = (const float4*)(h1s + (size_t)(v0 + v) * NF1);
    float4* orow = (float4*)(as2 + (size_t)(v0 + v) * NF1);
    const float* ar = &acc[v * ASTR];
#pragma unroll
    for (int i = 0; i < 4; ++i) {
      float4 hv = hr[i];
      float t0 = fmaf(dv, ar[4 * i + 0] + hv.x, b1s[4 * i + 0]);
      float t1 = fmaf(dv, ar[4 * i + 1] + hv.y, b1s[4 * i + 1]);
      float t2 = fmaf(dv, ar[4 * i + 2] + hv.z, b1s[4 * i + 2]);
      float t3 = fmaf(dv, ar[4 * i + 3] + hv.w, b1s[4 * i + 3]);
      orow[i] = make_float4((t0 > 0.f ? t0 : 0.f) * dv, (t1 > 0.f ? t1 : 0.f) * dv,
                            (t2 > 0.f ? t2 : 0.f) * dv, (t3 > 0.f ? t3 : 0.f) * dv);
    }
  }
}

// ---------------- layer-2 aggregation fused with W2 + b2 + log_softmax ----------------
__global__ __launch_bounds__(512) void k_aggL2fin(
    const unsigned int* __restrict__ ebuf, const int* __restrict__ boff,
    const float* __restrict__ as2, const float* __restrict__ dinv,
    const float* __restrict__ W2, const float* __restrict__ b2,
    float* __restrict__ out, int n) {
  __shared__ float acc[256 * ASTR];
  __shared__ float W2s[NF1 * NF2];
  __shared__ float b2s[NF2];
  for (int i = threadIdx.x; i < NF1 * NF2; i += 512) W2s[i] = W2[i];
  if (threadIdx.x < NF2) b2s[threadIdx.x] = b2[threadIdx.x];
  for (int i = threadIdx.x; i < 256 * ASTR; i += 512) acc[i] = 0.f;
  __syncthreads();
  int b = blockIdx.x;
  int e1 = boff[b + 1];
  for (int e = boff[b] + threadIdx.x; e < e1; e += 512) {
    unsigned p = ebuf[e];
    int s = p & 0x1FFFF;
    int dl = p >> 17;
    const float4* hr = (const float4*)(as2 + (size_t)s * NF1);
    float4 a0 = hr[0], a1 = hr[1], a2 = hr[2], a3 = hr[3];
    float* ar = &acc[dl * ASTR];
    atomicAdd(&ar[0], a0.x);  atomicAdd(&ar[1], a0.y);
    atomicAdd(&ar[2], a0.z);  atomicAdd(&ar[3], a0.w);
    atomicAdd(&ar[4], a1.x);  atomicAdd(&ar[5], a1.y);
    atomicAdd(&ar[6], a1.z);  atomicAdd(&ar[7], a1.w);
    atomicAdd(&ar[8], a2.x);  atomicAdd(&ar[9], a2.y);
    atomicAdd(&ar[10], a2.z); atomicAdd(&ar[11], a2.w);
    atomicAdd(&ar[12], a3.x); atomicAdd(&ar[13], a3.y);
    atomicAdd(&ar[14], a3.z); atomicAdd(&ar[15], a3.w);
  }
  __syncthreads();
  int v0 = b << BK_LG;
  int nn = min(256, n - v0);
  for (int v = threadIdx.x; v < nn; v += 512) {
    float dv = dinv[v0 + v];
    const float4* hr = (const float4*)(as2 + (size_t)(v0 + v) * NF1);
    const float* ar = &acc[v * ASTR];
    float a[NF1];
#pragma unroll
    for (int i = 0; i < 4; ++i) {
      float4 hv = hr[i];
      a[4 * i + 0] = dv * (ar[4 * i + 0] + hv.x);
      a[4 * i + 1] = dv * (ar[4 * i + 1] + hv.y);
      a[4 * i + 2] = dv * (ar[4 * i + 2] + hv.z);
      a[4 * i + 3] = dv * (ar[4 * i + 3] + hv.w);
    }
    float z[NF2];
    float m = -1e30f;
#pragma unroll
    for (int g = 0; g < NF2; ++g) {
      float t = b2s[g];
#pragma unroll
      for (int f = 0; f < NF1; ++f) t = fmaf(a[f], W2s[f * NF2 + g], t);
      z[g] = t;
      m = fmaxf(m, t);
    }
    float sum = 0.f;
#pragma unroll
    for (int g = 0; g < NF2; ++g) sum += __expf(z[g] - m);
    float ls = m + __logf(sum);
    float4* orow = (float4*)(out + (size_t)(v0 + v) * NF2);
#pragma unroll
    for (int i = 0; i < NF2 / 4; ++i)
      orow[i] = make_float4(z[4 * i] - ls, z[4 * i + 1] - ls,
                            z[4 * i + 2] - ls, z[4 * i + 3] - ls);
  }
}

extern "C" void kernel_launch(void* const* d_in, const int* in_sizes, int n_in,
                              void* d_out, int out_size, void* d_ws, size_t ws_size,
                              hipStream_t stream) {
  const float* x  = (const float*)d_in[0];
  const int*   ei = (const int*)d_in[1];
  const float* W1 = (const float*)d_in[2];
  const float* b1 = (const float*)d_in[3];
  const float* W2 = (const float*)d_in[4];
  const float* b2 = (const float*)d_in[5];
  int n = in_sizes[0] / NFEAT_IN;  // 100000
  int E = in_sizes[1] / 2;         // 3200000
  const int* src = ei;
  const int* dst = ei + E;
  float* out = (float*)d_out;
  int nbk = (n + 255) >> BK_LG;    // 391

  char* ws = (char*)d_ws;
  size_t off = 0;
  auto alloc = [&](size_t bytes) { size_t o = off; off = (off + bytes + 63) & ~63ULL; return o; };
  int*   deg  = (int*)(ws + alloc((size_t)n * 4));
  float* dinv = (float*)(ws + alloc((size_t)n * 4));
  int*   bsz  = (int*)(ws + alloc(512 * 4));
  int*   boff = (int*)(ws + alloc(513 * 4));
  int*   gcur = (int*)(ws + alloc(512 * 4));
  unsigned int* ebuf = (unsigned int*)(ws + alloc((size_t)E * 4));
  float* h1s  = (float*)(ws + alloc((size_t)n * NF1 * 4));
  float* as2  = (float*)(ws + alloc((size_t)n * NF1 * 4));

  hipMemsetAsync(deg, 0, (size_t)n * 4, stream);

  k_count<<<(E + 255) / 256, 256, 0, stream>>>(dst, deg, E);
  k_dinv <<<(n + 255) / 256, 256, 0, stream>>>(deg, dinv, n);
  k_bsz  <<<nbk, 256, 0, stream>>>(deg, bsz, n);
  k_scanb<<<1, 512, 0, stream>>>(bsz, boff, gcur, nbk, E);
  k_part <<<P1B, 256, 0, stream>>>(src, dst, gcur, ebuf, E, nbk);
  k_gemm1<<<((size_t)n * NF1 + 255) / 256, 256, 0, stream>>>(x, W1, dinv, h1s, n);
  k_aggL1<<<nbk, 512, 0, stream>>>(ebuf, boff, h1s, dinv, b1, as2, n);
  k_aggL2fin<<<nbk, 512, 0, stream>>>(ebuf, boff, as2, dinv, W2, b2, out, n);
}

// Round 5
// 581.153 us; speedup vs baseline: 2.1755x; 2.1755x over previous
//
#include <hip/hip_runtime.h>
#include <hip/hip_fp16.h>

// 2-layer GCN, N=100000, E=3200000, feats 512 -> 16 -> 40.
// out[d] = dinv[d]*(sum_{s->d} h[s]*dinv[s] + h[d]*dinv[d]) + b,  dinv = rsqrt(deg+1)
//
// Round-5 structure:
//  * CSR built scatter-free-ish: bucket partition (dense writes) + per-bucket LDS
//    sort (k_sortb; scatter confined to 33KB L2-hot windows). deg/dinv/rp fall out
//    of the bucket histogram -> k_count/k_dinv eliminated.
//  * Aggregation: node-parallel CSR walk, 16 lanes/node, register sums, unroll-8
//    (round-4's 391-block LDS-atomic agg was latency-bound at 27% occupancy).
//  * h1s/as2 gather tables in fp16 (3.2MB -> fits 4MB per-XCD L2).
//  * Layer-2 agg fuses W2 + b2 + log_softmax (LDS transpose + shfl_xor width-16).

#define NFEAT_IN 512
#define NF1 16
#define NF2 40
#define BK_LG 8           // 256 nodes per bucket
#define TILE 8192         // edges per partition tile

// ---------------- per-bucket edge histogram ----------------
__global__ void k_bhist(const int* __restrict__ dst, int* __restrict__ gbsz, int E, int nbk) {
  __shared__ int h[512];
  for (int i = threadIdx.x; i < nbk; i += 256) h[i] = 0;
  __syncthreads();
  int stride = gridDim.x * 256;
  for (int e = blockIdx.x * 256 + threadIdx.x; e < E; e += stride)
    atomicAdd(&h[dst[e] >> BK_LG], 1);
  __syncthreads();
  for (int i = threadIdx.x; i < nbk; i += 256)
    if (h[i]) atomicAdd(&gbsz[i], h[i]);
}

// ---------------- scan bucket sizes (nbk <= 512), one block ----------------
__global__ void k_scanb(const int* __restrict__ gbsz, int* __restrict__ boff,
                        int* __restrict__ gcur, int* __restrict__ rp,
                        int nbk, int n, int E) {
  __shared__ int s[512];
  int t = threadIdx.x;
  s[t] = (t < nbk) ? gbsz[t] : 0;
  __syncthreads();
  for (int o = 1; o < 512; o <<= 1) {
    int v = (t >= o) ? s[t - o] : 0;
    __syncthreads();
    s[t] += v;
    __syncthreads();
  }
  if (t < nbk) {
    int ex = s[t] - gbsz[t];
    boff[t] = ex;
    gcur[t] = ex;
  }
  if (t == 0) { boff[nbk] = E; rp[n] = E; }
}

// ---------------- bucket partition: ebuf[] = (dst&255)<<17 | src ----------------
__global__ void k_part(const int* __restrict__ src, const int* __restrict__ dst,
                       int* __restrict__ gcur, unsigned int* __restrict__ ebuf,
                       int E, int nbk) {
  __shared__ int hist[512];
  __shared__ int hbase[512];
  int chunk = (E + gridDim.x - 1) / gridDim.x;
  int beg = blockIdx.x * chunk;
  int end = min(E, beg + chunk);
  for (int t0 = beg; t0 < end; t0 += TILE) {
    int t1 = min(end, t0 + TILE);
    for (int i = threadIdx.x; i < nbk; i += 256) hist[i] = 0;
    __syncthreads();
    for (int i = t0 + threadIdx.x; i < t1; i += 256)
      atomicAdd(&hist[dst[i] >> BK_LG], 1);
    __syncthreads();
    for (int i = threadIdx.x; i < nbk; i += 256) {
      int c = hist[i];
      hbase[i] = c ? atomicAdd(&gcur[i], c) : 0;
      hist[i] = 0;  // becomes rank counter
    }
    __syncthreads();
    for (int i = t0 + threadIdx.x; i < t1; i += 256) {
      int d = dst[i];
      int b = d >> BK_LG;
      int r = atomicAdd(&hist[b], 1);
      ebuf[hbase[b] + r] = ((unsigned)(d & ((1 << BK_LG) - 1)) << 17) | (unsigned)src[i];
    }
    __syncthreads();
  }
}

// ---------------- per-bucket sort to CSR + deg/dinv/rp ----------------
// Scatter targets lie in a ~33KB global window -> lines stay hot in L2.
__global__ __launch_bounds__(256) void k_sortb(
    const unsigned int* __restrict__ ebuf, const int* __restrict__ boff,
    int* __restrict__ esrc, int* __restrict__ rp, float* __restrict__ dinv,
    int n) {
  __shared__ int hist[256];
  __shared__ int scan[256];
  __shared__ int cur[256];
  int b = blockIdx.x;
  int e0 = boff[b], e1 = boff[b + 1];
  hist[threadIdx.x] = 0;
  __syncthreads();
  for (int e = e0 + threadIdx.x; e < e1; e += 256)
    atomicAdd(&hist[ebuf[e] >> 17], 1);
  __syncthreads();
  scan[threadIdx.x] = hist[threadIdx.x];
  __syncthreads();
  for (int o = 1; o < 256; o <<= 1) {
    int v = (threadIdx.x >= o) ? scan[threadIdx.x - o] : 0;
    __syncthreads();
    scan[threadIdx.x] += v;
    __syncthreads();
  }
  int excl = scan[threadIdx.x] - hist[threadIdx.x];
  cur[threadIdx.x] = e0 + excl;
  int vg = (b << BK_LG) + threadIdx.x;
  if (vg < n) {
    rp[vg] = e0 + excl;
    dinv[vg] = rsqrtf((float)(hist[threadIdx.x] + 1));  // +1 self-loop
  }
  __syncthreads();
  for (int e = e0 + threadIdx.x; e < e1; e += 256) {
    unsigned p = ebuf[e];
    int pos = atomicAdd(&cur[p >> 17], 1);
    esrc[pos] = (int)(p & 0x1FFFF);
  }
}

// ---------------- layer-1 gemm: h1s[v][f] = fp16( dinv[v]*sum_k x[v][k]*W1[k][f] ) ----------------
__global__ void k_gemm1(const float* __restrict__ x, const float* __restrict__ W1,
                        const float* __restrict__ dinv, __half* __restrict__ h1s, int n) {
  __shared__ float Wt[NF1][NFEAT_IN + 4];
  for (int i = threadIdx.x; i < NFEAT_IN * NF1; i += 256) {
    int k = i >> 4, f = i & 15;
    Wt[f][k] = W1[i];
  }
  __syncthreads();
  int tid = blockIdx.x * 256 + threadIdx.x;
  int v = tid >> 4, f = tid & 15;
  const float4* xr = (const float4*)(x + (size_t)v * NFEAT_IN);
  const float4* wr = (const float4*)(&Wt[f][0]);
  float acc = 0.f;
#pragma unroll 8
  for (int k4 = 0; k4 < NFEAT_IN / 4; ++k4) {
    float4 a = xr[k4], w = wr[k4];
    acc = fmaf(a.x, w.x, acc);
    acc = fmaf(a.y, w.y, acc);
    acc = fmaf(a.z, w.z, acc);
    acc = fmaf(a.w, w.w, acc);
  }
  h1s[tid] = __float2half(acc * dinv[v]);
}

// ---------------- layer-1 agg: as2 = fp16( relu(dinv*(agg+self)+b1)*dinv ) ----------------
__global__ __launch_bounds__(256) void k_agg1(
    const int* __restrict__ rp, const int* __restrict__ esrc,
    const __half* __restrict__ h, const float* __restrict__ dinv,
    const float* __restrict__ b1, __half* __restrict__ as2) {
  int t = blockIdx.x * 256 + threadIdx.x;
  int v = t >> 4, f = t & 15;
  int beg = rp[v], end = rp[v + 1];
  float sum = __half2float(h[t]);  // self-loop (pre-scaled)
  int e = beg;
  for (; e + 8 <= end; e += 8) {  // 8 gathers in flight
    int s0 = esrc[e],     s1 = esrc[e + 1], s2 = esrc[e + 2], s3 = esrc[e + 3];
    int s4 = esrc[e + 4], s5 = esrc[e + 5], s6 = esrc[e + 6], s7 = esrc[e + 7];
    float a0 = __half2float(h[(size_t)s0 * NF1 + f]);
    float a1 = __half2float(h[(size_t)s1 * NF1 + f]);
    float a2 = __half2float(h[(size_t)s2 * NF1 + f]);
    float a3 = __half2float(h[(size_t)s3 * NF1 + f]);
    float a4 = __half2float(h[(size_t)s4 * NF1 + f]);
    float a5 = __half2float(h[(size_t)s5 * NF1 + f]);
    float a6 = __half2float(h[(size_t)s6 * NF1 + f]);
    float a7 = __half2float(h[(size_t)s7 * NF1 + f]);
    sum += ((a0 + a1) + (a2 + a3)) + ((a4 + a5) + (a6 + a7));
  }
  for (; e < end; ++e) sum += __half2float(h[(size_t)esrc[e] * NF1 + f]);
  float dv = dinv[v];
  float a = fmaf(dv, sum, b1[f]);
  as2[t] = __float2half((a > 0.f ? a : 0.f) * dv);
}

// ---------------- layer-2 agg fused with W2 + b2 + log_softmax ----------------
// lane f of a 16-lane group holds feature f of node v; W2 applied after an LDS
// transpose; max/sumexp via shfl_xor width 16.
__global__ __launch_bounds__(256) void k_agg2fin(
    const int* __restrict__ rp, const int* __restrict__ esrc,
    const __half* __restrict__ h, const float* __restrict__ dinv,
    const float* __restrict__ W2, const float* __restrict__ b2,
    float* __restrict__ out) {
  __shared__ float W2s[NF1 * NF2];
  __shared__ float b2s[NF2];
  __shared__ float sa[256];  // [16 nodes][16 feats]
  for (int i = threadIdx.x; i < NF1 * NF2; i += 256) W2s[i] = W2[i];
  if (threadIdx.x < NF2) b2s[threadIdx.x] = b2[threadIdx.x];
  int t = blockIdx.x * 256 + threadIdx.x;
  int v = t >> 4, f = t & 15;
  int beg = rp[v], end = rp[v + 1];
  float sum = __half2float(h[t]);
  int e = beg;
  for (; e + 8 <= end; e += 8) {
    int s0 = esrc[e],     s1 = esrc[e + 1], s2 = esrc[e + 2], s3 = esrc[e + 3];
    int s4 = esrc[e + 4], s5 = esrc[e + 5], s6 = esrc[e + 6], s7 = esrc[e + 7];
    float a0 = __half2float(h[(size_t)s0 * NF1 + f]);
    float a1 = __half2float(h[(size_t)s1 * NF1 + f]);
    float a2 = __half2float(h[(size_t)s2 * NF1 + f]);
    float a3 = __half2float(h[(size_t)s3 * NF1 + f]);
    float a4 = __half2float(h[(size_t)s4 * NF1 + f]);
    float a5 = __half2float(h[(size_t)s5 * NF1 + f]);
    float a6 = __half2float(h[(size_t)s6 * NF1 + f]);
    float a7 = __half2float(h[(size_t)s7 * NF1 + f]);
    sum += ((a0 + a1) + (a2 + a3)) + ((a4 + a5) + (a6 + a7));
  }
  for (; e < end; ++e) sum += __half2float(h[(size_t)esrc[e] * NF1 + f]);
  sa[threadIdx.x] = dinv[v] * sum;  // fully-normalized pre-W2 feature
  __syncthreads();
  const float* av = &sa[(threadIdx.x >> 4) << 4];
  float z0 = b2s[f], z1 = b2s[f + 16], z2 = (f < 8) ? b2s[f + 32] : -1e30f;
#pragma unroll
  for (int ff = 0; ff < NF1; ++ff) {
    float a = av[ff];
    z0 = fmaf(a, W2s[ff * NF2 + f], z0);
    z1 = fmaf(a, W2s[ff * NF2 + f + 16], z1);
    if (f < 8) z2 = fmaf(a, W2s[ff * NF2 + f + 32], z2);
  }
  float m = fmaxf(fmaxf(z0, z1), z2);
#pragma unroll
  for (int o = 8; o > 0; o >>= 1) m = fmaxf(m, __shfl_xor(m, o, 16));
  float s = __expf(z0 - m) + __expf(z1 - m) + ((f < 8) ? __expf(z2 - m) : 0.f);
#pragma unroll
  for (int o = 8; o > 0; o >>= 1) s += __shfl_xor(s, o, 16);
  float ls = m + __logf(s);
  float* orow = out + (size_t)v * NF2;
  orow[f] = z0 - ls;
  orow[f + 16] = z1 - ls;
  if (f < 8) orow[f + 32] = z2 - ls;
}

extern "C" void kernel_launch(void* const* d_in, const int* in_sizes, int n_in,
                              void* d_out, int out_size, void* d_ws, size_t ws_size,
                              hipStream_t stream) {
  const float* x  = (const float*)d_in[0];
  const int*   ei = (const int*)d_in[1];
  const float* W1 = (const float*)d_in[2];
  const float* b1 = (const float*)d_in[3];
  const float* W2 = (const float*)d_in[4];
  const float* b2 = (const float*)d_in[5];
  int n = in_sizes[0] / NFEAT_IN;  // 100000  (n*NF1 is a multiple of 256)
  int E = in_sizes[1] / 2;         // 3200000
  const int* src = ei;
  const int* dst = ei + E;
  float* out = (float*)d_out;
  int nbk = ((n - 1) >> BK_LG) + 1;  // 391

  char* ws = (char*)d_ws;
  size_t off = 0;
  auto alloc = [&](size_t bytes) { size_t o = off; off = (off + bytes + 63) & ~63ULL; return o; };
  int*   gbsz = (int*)(ws + alloc(512 * 4));
  int*   boff = (int*)(ws + alloc(513 * 4));
  int*   gcur = (int*)(ws + alloc(512 * 4));
  int*   rp   = (int*)(ws + alloc((size_t)(n + 1) * 4));
  float* dinv = (float*)(ws + alloc((size_t)n * 4));
  unsigned int* ebuf = (unsigned int*)(ws + alloc((size_t)E * 4));
  int*   esrc = (int*)(ws + alloc((size_t)E * 4));
  __half* h1s = (__half*)(ws + alloc((size_t)n * NF1 * 2));
  __half* as2 = (__half*)(ws + alloc((size_t)n * NF1 * 2));

  hipMemsetAsync(gbsz, 0, 512 * 4, stream);

  k_bhist<<<1024, 256, 0, stream>>>(dst, gbsz, E, nbk);
  k_scanb<<<1, 512, 0, stream>>>(gbsz, boff, gcur, rp, nbk, n, E);
  k_part <<<256, 256, 0, stream>>>(src, dst, gcur, ebuf, E, nbk);
  k_sortb<<<nbk, 256, 0, stream>>>(ebuf, boff, esrc, rp, dinv, n);
  k_gemm1<<<((size_t)n * NF1) / 256, 256, 0, stream>>>(x, W1, dinv, h1s, n);
  k_agg1 <<<((size_t)n * NF1) / 256, 256, 0, stream>>>(rp, esrc, h1s, dinv, b1, as2);
  k_agg2fin<<<((size_t)n * NF1) / 256, 256, 0, stream>>>(rp, esrc, as2, dinv, W2, b2, out);
}

// Round 8
// 488.692 us; speedup vs baseline: 2.5871x; 1.1892x over previous
//
#include <hip/hip_runtime.h>
#include <hip/hip_fp16.h>

// 2-layer GCN, N=100000, E=3200000, feats 512 -> 16 -> 40.
// out[d] = dinv[d]*(sum_{s->d} h[s]*dinv[s] + h[d]*dinv[d]) + b,  dinv = rsqrt(deg+1)
//
// Round-6: k_gemm1 rebuilt on v_mfma_f32_16x16x32_f16 (round-5 version was
// request-path bound: 16 lanes/row -> 64B useful per VMEM instr, 173us).
// One wave = one 16-node x 16-feat tile; x staged fp32->fp16 in LDS via
// coalesced float4; W1 transposed to LDS once per block; fp32 accumulate.
// CSR build + gather aggregation unchanged from round 5.

#define NFEAT_IN 512
#define NF1 16
#define NF2 40
#define BK_LG 8           // 256 nodes per bucket
#define TILE 8192         // edges per partition tile
#define XSTR 264          // xs row stride in halfs (256 + 8; 16B-aligned rows)
#define WSTR 520          // Wt row stride in halfs (512 + 8; 16B-aligned rows)

typedef _Float16 f16x8 __attribute__((ext_vector_type(8)));
typedef _Float16 f16x4 __attribute__((ext_vector_type(4)));
typedef float f32x4 __attribute__((ext_vector_type(4)));

// ---------------- per-bucket edge histogram ----------------
__global__ void k_bhist(const int* __restrict__ dst, int* __restrict__ gbsz, int E, int nbk) {
  __shared__ int h[512];
  for (int i = threadIdx.x; i < nbk; i += 256) h[i] = 0;
  __syncthreads();
  int stride = gridDim.x * 256;
  for (int e = blockIdx.x * 256 + threadIdx.x; e < E; e += stride)
    atomicAdd(&h[dst[e] >> BK_LG], 1);
  __syncthreads();
  for (int i = threadIdx.x; i < nbk; i += 256)
    if (h[i]) atomicAdd(&gbsz[i], h[i]);
}

// ---------------- scan bucket sizes (nbk <= 512), one block ----------------
__global__ void k_scanb(const int* __restrict__ gbsz, int* __restrict__ boff,
                        int* __restrict__ gcur, int* __restrict__ rp,
                        int nbk, int n, int E) {
  __shared__ int s[512];
  int t = threadIdx.x;
  s[t] = (t < nbk) ? gbsz[t] : 0;
  __syncthreads();
  for (int o = 1; o < 512; o <<= 1) {
    int v = (t >= o) ? s[t - o] : 0;
    __syncthreads();
    s[t] += v;
    __syncthreads();
  }
  if (t < nbk) {
    int ex = s[t] - gbsz[t];
    boff[t] = ex;
    gcur[t] = ex;
  }
  if (t == 0) { boff[nbk] = E; rp[n] = E; }
}

// ---------------- bucket partition: ebuf[] = (dst&255)<<17 | src ----------------
__global__ void k_part(const int* __restrict__ src, const int* __restrict__ dst,
                       int* __restrict__ gcur, unsigned int* __restrict__ ebuf,
                       int E, int nbk) {
  __shared__ int hist[512];
  __shared__ int hbase[512];
  int chunk = (E + gridDim.x - 1) / gridDim.x;
  int beg = blockIdx.x * chunk;
  int end = min(E, beg + chunk);
  for (int t0 = beg; t0 < end; t0 += TILE) {
    int t1 = min(end, t0 + TILE);
    for (int i = threadIdx.x; i < nbk; i += 256) hist[i] = 0;
    __syncthreads();
    for (int i = t0 + threadIdx.x; i < t1; i += 256)
      atomicAdd(&hist[dst[i] >> BK_LG], 1);
    __syncthreads();
    for (int i = threadIdx.x; i < nbk; i += 256) {
      int c = hist[i];
      hbase[i] = c ? atomicAdd(&gcur[i], c) : 0;
      hist[i] = 0;  // becomes rank counter
    }
    __syncthreads();
    for (int i = t0 + threadIdx.x; i < t1; i += 256) {
      int d = dst[i];
      int b = d >> BK_LG;
      int r = atomicAdd(&hist[b], 1);
      ebuf[hbase[b] + r] = ((unsigned)(d & ((1 << BK_LG) - 1)) << 17) | (unsigned)src[i];
    }
    __syncthreads();
  }
}

// ---------------- per-bucket sort to CSR + deg/dinv/rp ----------------
__global__ __launch_bounds__(256) void k_sortb(
    const unsigned int* __restrict__ ebuf, const int* __restrict__ boff,
    int* __restrict__ esrc, int* __restrict__ rp, float* __restrict__ dinv,
    int n) {
  __shared__ int hist[256];
  __shared__ int scan[256];
  __shared__ int cur[256];
  int b = blockIdx.x;
  int e0 = boff[b], e1 = boff[b + 1];
  hist[threadIdx.x] = 0;
  __syncthreads();
  for (int e = e0 + threadIdx.x; e < e1; e += 256)
    atomicAdd(&hist[ebuf[e] >> 17], 1);
  __syncthreads();
  scan[threadIdx.x] = hist[threadIdx.x];
  __syncthreads();
  for (int o = 1; o < 256; o <<= 1) {
    int v = (threadIdx.x >= o) ? scan[threadIdx.x - o] : 0;
    __syncthreads();
    scan[threadIdx.x] += v;
    __syncthreads();
  }
  int excl = scan[threadIdx.x] - hist[threadIdx.x];
  cur[threadIdx.x] = e0 + excl;
  int vg = (b << BK_LG) + threadIdx.x;
  if (vg < n) {
    rp[vg] = e0 + excl;
    dinv[vg] = rsqrtf((float)(hist[threadIdx.x] + 1));  // +1 self-loop
  }
  __syncthreads();
  for (int e = e0 + threadIdx.x; e < e1; e += 256) {
    unsigned p = ebuf[e];
    int pos = atomicAdd(&cur[p >> 17], 1);
    esrc[pos] = (int)(p & 0x1FFFF);
  }
}

// ---------------- layer-1 gemm via MFMA ----------------
// One wave per 16-node tile.  A = x-tile (16x512 fp16, LDS-staged in K-halves),
// B = W1 (Wt[f][k] fp16 in LDS, transposed once per block).  D = A.B fp32.
// Fragment maps (16x16x32): A: row=l&15, k=(l>>4)*8+j ; B: col=l&15, k=(l>>4)*8+j ;
// C/D: col=l&15, row=(l>>4)*4+q  [m89-verified].
__global__ __launch_bounds__(256) void k_gemm1(
    const float* __restrict__ x, const float* __restrict__ W1,
    const float* __restrict__ dinv, __half* __restrict__ h1s, int ntiles) {
  __shared__ _Float16 Wt[NF1 * WSTR];        // 16.6 KB
  __shared__ _Float16 xs[4][16 * XSTR];      // 4 x 8.4 KB (per-wave tile buffer)
  for (int i = threadIdx.x; i < NFEAT_IN * NF1; i += 256) {
    int k = i >> 4, f = i & 15;
    Wt[f * WSTR + k] = (_Float16)W1[i];
  }
  __syncthreads();

  int w = threadIdx.x >> 6;        // wave in block
  int l = threadIdx.x & 63;        // lane
  int tile = blockIdx.x * 4 + w;
  if (tile >= ntiles) return;
  int v0 = tile << 4;

  int fr = l & 15;                 // A row / B col / D col
  int kb = l >> 4;                 // k-block within fragment
  _Float16* xsw = &xs[w][0];
  const _Float16* xrow = &xsw[fr * XSTR + (kb << 3)];
  const _Float16* wrow = &Wt[fr * WSTR + (kb << 3)];

  f32x4 acc = {0.f, 0.f, 0.f, 0.f};
#pragma unroll
  for (int half = 0; half < 2; ++half) {
    // stage 16 rows x 256 cols, coalesced: iter i reads row i's contiguous 1KB chunk
#pragma unroll
    for (int i = 0; i < 16; ++i) {
      float4 a = *(const float4*)&x[(size_t)(v0 + i) * NFEAT_IN + half * 256 + l * 4];
      f16x4 hv = {(_Float16)a.x, (_Float16)a.y, (_Float16)a.z, (_Float16)a.w};
      *(f16x4*)&xsw[i * XSTR + l * 4] = hv;
    }
    // compiler inserts lgkmcnt/vmcnt waits (same-wave dependency, no barrier needed)
#pragma unroll
    for (int kk = 0; kk < 8; ++kk) {
      f16x8 av = *(const f16x8*)&xrow[kk * 32];
      f16x8 bv = *(const f16x8*)&wrow[half * 256 + kk * 32];
      acc = __builtin_amdgcn_mfma_f32_16x16x32_f16(av, bv, acc, 0, 0, 0);
    }
  }
  // epilogue: D[row][col] -> h1s[v0+row][col] * dinv
  int rbase = kb << 2;
#pragma unroll
  for (int q = 0; q < 4; ++q) {
    int v = v0 + rbase + q;
    h1s[(size_t)v * NF1 + fr] = __float2half(acc[q] * dinv[v]);
  }
}

// ---------------- layer-1 agg: as2 = fp16( relu(dinv*(agg+self)+b1)*dinv ) ----------------
__global__ __launch_bounds__(256) void k_agg1(
    const int* __restrict__ rp, const int* __restrict__ esrc,
    const __half* __restrict__ h, const float* __restrict__ dinv,
    const float* __restrict__ b1, __half* __restrict__ as2) {
  int t = blockIdx.x * 256 + threadIdx.x;
  int v = t >> 4, f = t & 15;
  int beg = rp[v], end = rp[v + 1];
  float sum = __half2float(h[t]);  // self-loop (pre-scaled)
  int e = beg;
  for (; e + 8 <= end; e += 8) {  // 8 gathers in flight
    int s0 = esrc[e],     s1 = esrc[e + 1], s2 = esrc[e + 2], s3 = esrc[e + 3];
    int s4 = esrc[e + 4], s5 = esrc[e + 5], s6 = esrc[e + 6], s7 = esrc[e + 7];
    float a0 = __half2float(h[(size_t)s0 * NF1 + f]);
    float a1 = __half2float(h[(size_t)s1 * NF1 + f]);
    float a2 = __half2float(h[(size_t)s2 * NF1 + f]);
    float a3 = __half2float(h[(size_t)s3 * NF1 + f]);
    float a4 = __half2float(h[(size_t)s4 * NF1 + f]);
    float a5 = __half2float(h[(size_t)s5 * NF1 + f]);
    float a6 = __half2float(h[(size_t)s6 * NF1 + f]);
    float a7 = __half2float(h[(size_t)s7 * NF1 + f]);
    sum += ((a0 + a1) + (a2 + a3)) + ((a4 + a5) + (a6 + a7));
  }
  for (; e < end; ++e) sum += __half2float(h[(size_t)esrc[e] * NF1 + f]);
  float dv = dinv[v];
  float a = fmaf(dv, sum, b1[f]);
  as2[t] = __float2half((a > 0.f ? a : 0.f) * dv);
}

// ---------------- layer-2 agg fused with W2 + b2 + log_softmax ----------------
__global__ __launch_bounds__(256) void k_agg2fin(
    const int* __restrict__ rp, const int* __restrict__ esrc,
    const __half* __restrict__ h, const float* __restrict__ dinv,
    const float* __restrict__ W2, const float* __restrict__ b2,
    float* __restrict__ out) {
  __shared__ float W2s[NF1 * NF2];
  __shared__ float b2s[NF2];
  __shared__ float sa[256];  // [16 nodes][16 feats]
  for (int i = threadIdx.x; i < NF1 * NF2; i += 256) W2s[i] = W2[i];
  if (threadIdx.x < NF2) b2s[threadIdx.x] = b2[threadIdx.x];
  int t = blockIdx.x * 256 + threadIdx.x;
  int v = t >> 4, f = t & 15;
  int beg = rp[v], end = rp[v + 1];
  float sum = __half2float(h[t]);
  int e = beg;
  for (; e + 8 <= end; e += 8) {
    int s0 = esrc[e],     s1 = esrc[e + 1], s2 = esrc[e + 2], s3 = esrc[e + 3];
    int s4 = esrc[e + 4], s5 = esrc[e + 5], s6 = esrc[e + 6], s7 = esrc[e + 7];
    float a0 = __half2float(h[(size_t)s0 * NF1 + f]);
    float a1 = __half2float(h[(size_t)s1 * NF1 + f]);
    float a2 = __half2float(h[(size_t)s2 * NF1 + f]);
    float a3 = __half2float(h[(size_t)s3 * NF1 + f]);
    float a4 = __half2float(h[(size_t)s4 * NF1 + f]);
    float a5 = __half2float(h[(size_t)s5 * NF1 + f]);
    float a6 = __half2float(h[(size_t)s6 * NF1 + f]);
    float a7 = __half2float(h[(size_t)s7 * NF1 + f]);
    sum += ((a0 + a1) + (a2 + a3)) + ((a4 + a5) + (a6 + a7));
  }
  for (; e < end; ++e) sum += __half2float(h[(size_t)esrc[e] * NF1 + f]);
  sa[threadIdx.x] = dinv[v] * sum;  // fully-normalized pre-W2 feature
  __syncthreads();
  const float* av = &sa[(threadIdx.x >> 4) << 4];
  float z0 = b2s[f], z1 = b2s[f + 16], z2 = (f < 8) ? b2s[f + 32] : -1e30f;
#pragma unroll
  for (int ff = 0; ff < NF1; ++ff) {
    float a = av[ff];
    z0 = fmaf(a, W2s[ff * NF2 + f], z0);
    z1 = fmaf(a, W2s[ff * NF2 + f + 16], z1);
    if (f < 8) z2 = fmaf(a, W2s[ff * NF2 + f + 32], z2);
  }
  float m = fmaxf(fmaxf(z0, z1), z2);
#pragma unroll
  for (int o = 8; o > 0; o >>= 1) m = fmaxf(m, __shfl_xor(m, o, 16));
  float s = __expf(z0 - m) + __expf(z1 - m) + ((f < 8) ? __expf(z2 - m) : 0.f);
#pragma unroll
  for (int o = 8; o > 0; o >>= 1) s += __shfl_xor(s, o, 16);
  float ls = m + __logf(s);
  float* orow = out + (size_t)v * NF2;
  orow[f] = z0 - ls;
  orow[f + 16] = z1 - ls;
  if (f < 8) orow[f + 32] = z2 - ls;
}

extern "C" void kernel_launch(void* const* d_in, const int* in_sizes, int n_in,
                              void* d_out, int out_size, void* d_ws, size_t ws_size,
                              hipStream_t stream) {
  const float* x  = (const float*)d_in[0];
  const int*   ei = (const int*)d_in[1];
  const float* W1 = (const float*)d_in[2];
  const float* b1 = (const float*)d_in[3];
  const float* W2 = (const float*)d_in[4];
  const float* b2 = (const float*)d_in[5];
  int n = in_sizes[0] / NFEAT_IN;  // 100000  (multiple of 16)
  int E = in_sizes[1] / 2;         // 3200000
  const int* src = ei;
  const int* dst = ei + E;
  float* out = (float*)d_out;
  int nbk = ((n - 1) >> BK_LG) + 1;   // 391
  int ntiles = n >> 4;                // 6250

  char* ws = (char*)d_ws;
  size_t off = 0;
  auto alloc = [&](size_t bytes) { size_t o = off; off = (off + bytes + 63) & ~63ULL; return o; };
  int*   gbsz = (int*)(ws + alloc(512 * 4));
  int*   boff = (int*)(ws + alloc(513 * 4));
  int*   gcur = (int*)(ws + alloc(512 * 4));
  int*   rp   = (int*)(ws + alloc((size_t)(n + 1) * 4));
  float* dinv = (float*)(ws + alloc((size_t)n * 4));
  unsigned int* ebuf = (unsigned int*)(ws + alloc((size_t)E * 4));
  int*   esrc = (int*)(ws + alloc((size_t)E * 4));
  __half* h1s = (__half*)(ws + alloc((size_t)n * NF1 * 2));
  __half* as2 = (__half*)(ws + alloc((size_t)n * NF1 * 2));

  hipMemsetAsync(gbsz, 0, 512 * 4, stream);

  k_bhist<<<1024, 256, 0, stream>>>(dst, gbsz, E, nbk);
  k_scanb<<<1, 512, 0, stream>>>(gbsz, boff, gcur, rp, nbk, n, E);
  k_part <<<256, 256, 0, stream>>>(src, dst, gcur, ebuf, E, nbk);
  k_sortb<<<nbk, 256, 0, stream>>>(ebuf, boff, esrc, rp, dinv, n);
  k_gemm1<<<(ntiles + 3) / 4, 256, 0, stream>>>(x, W1, dinv, h1s, ntiles);
  k_agg1 <<<((size_t)n * NF1) / 256, 256, 0, stream>>>(rp, esrc, h1s, dinv, b1, as2);
  k_agg2fin<<<((size_t)n * NF1) / 256, 256, 0, stream>>>(rp, esrc, as2, dinv, W2, b2, out);
}